// Round 9
// baseline (8726.827 us; speedup 1.0000x reference)
//
#include <hip/hip_runtime.h>
#include <stdint.h>

// GRU scan, persistent cooperative kernel, round 9.
// Round 8 topology (32 clusters x 32 rows x 8 blocks, NT=256, wave owns 16
// cols, all W_hh in regs, LDS = 32KB A-tile) + row-half phase skew:
//   phase1 (rows 0-15) gated only on producers' LO flags (posted mid-step);
//   HI wait + hi-stage moved AFTER phase1 (hi flags posted end-of-prev-step,
//   so never block; stage latency hides under gates-lo). Per-wave flags
//   (no post barrier), flag preloads (no poll round trip when satisfied),
//   logits self-staged rows -> stay at step end barrier-free.
// Coherence: write-through h stores (RELAXED/AGENT), aux=17 read-through
// staging, relaxed flags, no fences (proven rounds 5-8).

#define NB 256
#define NT 256
#define TB 1024
#define TT 2048
#define II 12
#define HH 512
#define NCL 32
#define GBLK 8
#define ROWS 32

#define HTILE_B (ROWS * HH * 2)               // 32 KiB per cluster per buffer
#define HBUF_B  ((size_t)NCL * HTILE_B)       // 1 MiB per buffer
#define BAR_OFF ((size_t)2 * HBUF_B)
#define WS_USED (BAR_OFF + (size_t)NCL * 256) // 64 flag words per cluster

#define LDSB (ROWS * 1024)                    // 32 KiB A-tile

#define GAS __attribute__((address_space(1)))
#define LAS __attribute__((address_space(3)))

typedef _Float16 half8 __attribute__((ext_vector_type(8)));
typedef float    f32x4 __attribute__((ext_vector_type(4)));

static __device__ __forceinline__ float fast_sigmoid(float x) {
  float e = exp2f(-1.44269504f * x);
  return __builtin_amdgcn_rcpf(1.0f + e);
}
static __device__ __forceinline__ float fast_tanh(float x) {
  float e = exp2f(2.88539008f * x);           // exp(2x)
  return 1.0f - 2.0f * __builtin_amdgcn_rcpf(1.0f + e);
}

// Poll 32 per-wave flag words lane-parallel (lanes duplicate x2), relaxed.
static __device__ __forceinline__ void wait_flags32(unsigned* f, unsigned tgt,
                                                    int* dead) {
  const int l = threadIdx.x & 63;
  long spin = 0;
  for (;;) {
    unsigned v = __hip_atomic_load(f + (l & 31), __ATOMIC_RELAXED,
                                   __HIP_MEMORY_SCOPE_AGENT);
    if (__all(v >= tgt)) break;
    if (++spin > (1L << 24)) { *dead = 1; break; }
  }
}

__global__ void __launch_bounds__(NT, 1)
gru_persistent(const float* __restrict__ hist,
               const float* __restrict__ w_ih,
               const float* __restrict__ w_hh,
               const float* __restrict__ w_out,
               const float* __restrict__ b_out,
               float* __restrict__ out,
               uint8_t* __restrict__ ws)
{
  extern __shared__ char smem[];
  char* ldsA = smem;
  const int bid = blockIdx.x;
  const int c   = bid & 31;          // cluster (32)
  const int g   = bid >> 5;          // block within cluster (8)
  const int tid = threadIdx.x;
  const int w   = tid >> 6;          // wave 0..3 -> col-tile
  const int l   = tid & 63;
  const int l15 = l & 15;
  const int l4  = l >> 4;
  const int crb = c * ROWS;
  unsigned* loF = (unsigned*)(ws + BAR_OFF) + (size_t)c * 64;  // words 0..31
  unsigned* hiF = loF + 32;                                    // words 32..63
  const int myflag = g * 4 + w;

  const int col0 = g * 64 + w * 16;  // wave's 16 output cols

  // ---- W_hh register B-fragments for r,z,n (16 K-slices each, static idx)
  half8 wr[16], wz[16], wn[16];
#pragma unroll
  for (int ks = 0; ks < 16; ++ks) {
    const size_t Rr = (size_t)(0 * HH + col0 + l15) * HH + ks * 32 + l4 * 8;
    const size_t Rz = (size_t)(1 * HH + col0 + l15) * HH + ks * 32 + l4 * 8;
    const size_t Rn = (size_t)(2 * HH + col0 + l15) * HH + ks * 32 + l4 * 8;
#pragma unroll
    for (int i = 0; i < 8; ++i) {
      wr[ks][i] = (_Float16)w_hh[Rr + i];
      wz[ks][i] = (_Float16)w_hh[Rz + i];
      wn[ks][i] = (_Float16)w_hh[Rn + i];
    }
  }

  // ---- w_ih register B-fragments (K window = x cols 0..31)
  half8 wih[3];
#pragma unroll
  for (int gt = 0; gt < 3; ++gt) {
    const int R = gt * HH + col0 + l15;
#pragma unroll
    for (int i = 0; i < 8; ++i) {
      const int k = l4 * 8 + i;
      wih[gt][i] = (_Float16)((k < II) ? w_ih[R * II + k] : 0.0f);
    }
  }

  // ---- w_out in registers
  const int jj = (l >> 4) & 1;
  float wor[32];
#pragma unroll
  for (int i = 0; i < 32; ++i) wor[i] = w_out[jj * HH + l15 * 32 + i];
  const float bo = b_out[jj];

  float hprev[2][4];
#pragma unroll
  for (int mt = 0; mt < 2; ++mt)
#pragma unroll
    for (int q = 0; q < 4; ++q) hprev[mt][q] = 0.0f;

  const int pcol = col0 + l15;
  int deadlock = 0;

  // ---- x prologue: prefetch x(0)
  f32x4 xn0[2], xn1[2];
#pragma unroll
  for (int mt = 0; mt < 2; ++mt) {
    xn0[mt] = (f32x4){0.f, 0.f, 0.f, 0.f};
    xn1[mt] = (f32x4){0.f, 0.f, 0.f, 0.f};
    const float* xp = hist + (size_t)(crb + mt * 16 + l15) * (TT * II);
    if (l4 == 0)      { xn0[mt] = *(const f32x4*)xp; xn1[mt] = *(const f32x4*)(xp + 4); }
    else if (l4 == 1) { xn0[mt] = *(const f32x4*)(xp + 8); }
  }

  unsigned preLo = 0, preHi = 0;

  for (int t = 0; t < TT; ++t) {
    const uint8_t* hsrc = ws + ((t & 1) ? HBUF_B : 0) + (size_t)c * HTILE_B;
    uint8_t*       hdst = ws + ((t & 1) ? 0 : HBUF_B) + (size_t)c * HTILE_B;

    // ---- #1 wait LO flags of h(t) (posted mid-step t-1; preloaded at #15)
    if (!__all(preLo >= (unsigned)t)) wait_flags32(loF, (unsigned)t, &deadlock);
    __builtin_amdgcn_sched_barrier(0);

    // ---- #2 stage lo rows 0-15 (16KB, 4 insts/wave)
#pragma unroll
    for (int it = 0; it < 4; ++it)
      __builtin_amdgcn_global_load_lds(
          (const GAS uint32_t*)(hsrc + it * 4096 + tid * 16),
          (LAS uint32_t*)(ldsA + it * 4096 + tid * 16), 16, 0, 17);
    __builtin_amdgcn_sched_barrier(0);

    // ---- #3 build x(t) fragments; issue x(t+1) prefetch; preload HI flags
    half8 ax[2];
#pragma unroll
    for (int mt = 0; mt < 2; ++mt)
#pragma unroll
      for (int i = 0; i < 4; ++i) {
        ax[mt][i]     = (_Float16)xn0[mt][i];
        ax[mt][4 + i] = (_Float16)xn1[mt][i];
      }
    {
      const int tx = (t + 1 < TT) ? (t + 1) : 0;
#pragma unroll
      for (int mt = 0; mt < 2; ++mt) {
        const float* xp = hist + (size_t)(crb + mt * 16 + l15) * (TT * II) + (size_t)tx * II;
        if (l4 == 0)      { xn0[mt] = *(const f32x4*)xp; xn1[mt] = *(const f32x4*)(xp + 4); }
        else if (l4 == 1) { xn0[mt] = *(const f32x4*)(xp + 8); }
      }
    }
    preHi = __hip_atomic_load(hiF + (l & 31), __ATOMIC_RELAXED,
                              __HIP_MEMORY_SCOPE_AGENT);
    __builtin_amdgcn_sched_barrier(0);

    // ---- #4 outstanding: lo4 + x6 + preHi1 = 11 -> vmcnt(7) = lo staged
    asm volatile("s_waitcnt vmcnt(7)" ::: "memory");
    __builtin_amdgcn_s_barrier();
    __builtin_amdgcn_sched_barrier(0);

    // ======== #5 phase 1: rows 0-15 (mt=0) ========
    f32x4 acc0 = (f32x4){0.f, 0.f, 0.f, 0.f};
    f32x4 acc1 = acc0, acc2 = acc0;
    f32x4 accin = __builtin_amdgcn_mfma_f32_16x16x32_f16(ax[0], wih[2],
                    (f32x4){0.f, 0.f, 0.f, 0.f}, 0, 0, 0);
    acc0 = __builtin_amdgcn_mfma_f32_16x16x32_f16(ax[0], wih[0], acc0, 0, 0, 0);
    acc1 = __builtin_amdgcn_mfma_f32_16x16x32_f16(ax[0], wih[1], acc1, 0, 0, 0);
#pragma unroll
    for (int ks = 0; ks < 16; ++ks) {
      const int ko = (ks * 64 + l4 * 16) ^ ((l15 & 7) << 4);
      half8 a = *(const half8*)(ldsA + l15 * 1024 + ko);
      acc0 = __builtin_amdgcn_mfma_f32_16x16x32_f16(a, wr[ks], acc0, 0, 0, 0);
      acc1 = __builtin_amdgcn_mfma_f32_16x16x32_f16(a, wz[ks], acc1, 0, 0, 0);
      acc2 = __builtin_amdgcn_mfma_f32_16x16x32_f16(a, wn[ks], acc2, 0, 0, 0);
    }

    // ---- #6 HI flags of h(t): posted end-of-step t-1 -> never blocks here
    if (!__all(preHi >= (unsigned)t)) wait_flags32(hiF, (unsigned)t, &deadlock);
    __builtin_amdgcn_sched_barrier(0);
#pragma unroll
    for (int it = 0; it < 4; ++it)    // stage hi rows 16-31 (hides under gates)
      __builtin_amdgcn_global_load_lds(
          (const GAS uint32_t*)(hsrc + 16384 + it * 4096 + tid * 16),
          (LAS uint32_t*)(ldsA + 16384 + it * 4096 + tid * 16), 16, 0, 17);
    __builtin_amdgcn_sched_barrier(0);

    // ---- #7 gates + stores, rows 0-15
#pragma unroll
    for (int q = 0; q < 4; ++q) {
      const int m = l4 * 4 + q;
      const float r  = fast_sigmoid(acc0[q]);
      const float z  = fast_sigmoid(acc1[q]);
      const float n  = fast_tanh(accin[q] + r * acc2[q]);
      const float hn = (1.0f - z) * n + z * hprev[0][q];
      hprev[0][q] = hn;
      const unsigned short hu = __builtin_bit_cast(unsigned short, (_Float16)hn);
      __hip_atomic_store(
          (unsigned short*)(hdst + m * 1024 + ((pcol * 2) ^ ((m & 7) << 4))),
          hu, __ATOMIC_RELAXED, __HIP_MEMORY_SCOPE_AGENT);
    }
    __builtin_amdgcn_sched_barrier(0);

    // ---- #8 drain: hi staged + lo stores landed (+x retired)
    asm volatile("s_waitcnt vmcnt(0)" ::: "memory");
    // ---- #9 post LO flag (per wave: own 16 cols x rows 0-15 done)
    if (l == 0)
      __hip_atomic_store(loF + myflag, (unsigned)(t + 1), __ATOMIC_RELAXED,
                         __HIP_MEMORY_SCOPE_AGENT);
    // ---- #10 all waves' hi-stage retired beyond this point
    __builtin_amdgcn_s_barrier();
    __builtin_amdgcn_sched_barrier(0);

    // ======== #11 phase 2: rows 16-31 (mt=1) ========
    acc0 = (f32x4){0.f, 0.f, 0.f, 0.f};
    acc1 = acc0; acc2 = acc0;
    accin = __builtin_amdgcn_mfma_f32_16x16x32_f16(ax[1], wih[2],
              (f32x4){0.f, 0.f, 0.f, 0.f}, 0, 0, 0);
    acc0 = __builtin_amdgcn_mfma_f32_16x16x32_f16(ax[1], wih[0], acc0, 0, 0, 0);
    acc1 = __builtin_amdgcn_mfma_f32_16x16x32_f16(ax[1], wih[1], acc1, 0, 0, 0);
#pragma unroll
    for (int ks = 0; ks < 16; ++ks) {
      const int ko = (ks * 64 + l4 * 16) ^ ((l15 & 7) << 4);
      half8 a = *(const half8*)(ldsA + (16 + l15) * 1024 + ko);
      acc0 = __builtin_amdgcn_mfma_f32_16x16x32_f16(a, wr[ks], acc0, 0, 0, 0);
      acc1 = __builtin_amdgcn_mfma_f32_16x16x32_f16(a, wz[ks], acc1, 0, 0, 0);
      acc2 = __builtin_amdgcn_mfma_f32_16x16x32_f16(a, wn[ks], acc2, 0, 0, 0);
    }
#pragma unroll
    for (int q = 0; q < 4; ++q) {
      const int m = 16 + l4 * 4 + q;
      const float r  = fast_sigmoid(acc0[q]);
      const float z  = fast_sigmoid(acc1[q]);
      const float n  = fast_tanh(accin[q] + r * acc2[q]);
      const float hn = (1.0f - z) * n + z * hprev[1][q];
      hprev[1][q] = hn;
      const unsigned short hu = __builtin_bit_cast(unsigned short, (_Float16)hn);
      __hip_atomic_store(
          (unsigned short*)(hdst + m * 1024 + ((pcol * 2) ^ ((m & 7) << 4))),
          hu, __ATOMIC_RELAXED, __HIP_MEMORY_SCOPE_AGENT);
    }

    // ---- #12 logits(t-1) from h(t); row g*4+w is staged by THIS wave
    if (t > 0) {
      const int lr  = g * 4 + w;
      const int row = crb + lr;
      float s = 0.0f;
#pragma unroll
      for (int c8 = 0; c8 < 4; ++c8) {
        half8 hv = *(const half8*)(ldsA + lr * 1024 +
                                   ((l15 * 64 + c8 * 16) ^ ((lr & 7) << 4)));
#pragma unroll
        for (int i = 0; i < 8; ++i) s += (float)hv[i] * wor[c8 * 8 + i];
      }
#pragma unroll
      for (int off = 1; off < 16; off <<= 1) s += __shfl_xor(s, off);
      if (l15 == 0 && l < 32) out[((size_t)row * TT + (t - 1)) * 2 + jj] = s + bo;
    }

    // ---- #13 drain hi stores, #14 post HI flag, #15 preload LO for t+1
    asm volatile("s_waitcnt vmcnt(0)" ::: "memory");
    if (l == 0)
      __hip_atomic_store(hiF + myflag, (unsigned)(t + 1), __ATOMIC_RELAXED,
                         __HIP_MEMORY_SCOPE_AGENT);
    preLo = __hip_atomic_load(loF + (l & 31), __ATOMIC_RELAXED,
                              __HIP_MEMORY_SCOPE_AGENT);
  }

  // ---- epilogue: stage h(TT), logits for t = TT-1, h_final
  wait_flags32(loF, (unsigned)TT, &deadlock);
  wait_flags32(hiF, (unsigned)TT, &deadlock);
  {
    const uint8_t* hsrc = ws + ((TT & 1) ? HBUF_B : 0) + (size_t)c * HTILE_B;
#pragma unroll
    for (int it = 0; it < 8; ++it)
      __builtin_amdgcn_global_load_lds(
          (const GAS uint32_t*)(hsrc + it * 4096 + tid * 16),
          (LAS uint32_t*)(ldsA + it * 4096 + tid * 16), 16, 0, 17);
    asm volatile("s_waitcnt vmcnt(0)" ::: "memory");
    __builtin_amdgcn_s_barrier();

    const int lr  = g * 4 + w;
    const int row = crb + lr;
    float s = 0.0f;
#pragma unroll
    for (int c8 = 0; c8 < 4; ++c8) {
      half8 hv = *(const half8*)(ldsA + lr * 1024 +
                                 ((l15 * 64 + c8 * 16) ^ ((lr & 7) << 4)));
#pragma unroll
      for (int i = 0; i < 8; ++i) s += (float)hv[i] * wor[c8 * 8 + i];
    }
#pragma unroll
    for (int off = 1; off < 16; off <<= 1) s += __shfl_xor(s, off);
    if (l15 == 0 && l < 32) out[((size_t)row * TT + (TT - 1)) * 2 + jj] = s + bo;
  }

  // ---- h_final from fp32 carried state
#pragma unroll
  for (int mt = 0; mt < 2; ++mt)
#pragma unroll
    for (int q = 0; q < 4; ++q) {
      const int m = mt * 16 + l4 * 4 + q;
      out[(size_t)TB * TT * 2 + (size_t)(crb + m) * HH + pcol] = hprev[mt][q];
    }
}

extern "C" void kernel_launch(void* const* d_in, const int* in_sizes, int n_in,
                              void* d_out, int out_size, void* d_ws, size_t ws_size,
                              hipStream_t stream) {
  (void)in_sizes; (void)n_in; (void)out_size;
  if (ws_size < WS_USED) return;

  const float* hist  = (const float*)d_in[0];
  const float* w_ih  = (const float*)d_in[1];
  const float* w_hh  = (const float*)d_in[2];
  const float* w_out = (const float*)d_in[3];
  const float* b_out = (const float*)d_in[4];
  float* out = (float*)d_out;
  uint8_t* ws = (uint8_t*)d_ws;

  hipMemsetAsync(d_ws, 0, WS_USED, stream);   // h0 = 0, flag words

  void* args[] = {(void*)&hist, (void*)&w_ih, (void*)&w_hh, (void*)&w_out,
                  (void*)&b_out, (void*)&out, (void*)&ws};
  hipError_t e = hipLaunchCooperativeKernel((const void*)gru_persistent,
                                            dim3(NB), dim3(NT), args,
                                            (unsigned)LDSB, stream);
  if (e != hipSuccess) {
    // Fallback: plain launch. 256 blocks at 1/CU on 256 CUs co-reside; the
    // flag spin has a deadlock bail-out so this cannot hang.
    gru_persistent<<<dim3(NB), dim3(NT), LDSB, stream>>>(
        hist, w_ih, w_hh, w_out, b_out, out, ws);
  }
}